// Round 1
// baseline (400.063 us; speedup 1.0000x reference)
//
#include <hip/hip_runtime.h>
#include <math.h>

#define N_TOK 4096
#define DMODEL 512
#define NHEAD 8
#define DHEAD 64
#define CTX 10

// ---------------------------------------------------------------------------
// Stage 1: fused Q/V projection GEMM.
// X[B*N, D] @ [Wq | Wv] -> Qb, Vb stored as [B, H, N, 64] (contiguous 256B rows)
// Tile: 128x128x8, 256 threads, 8x8 micro-tile in split-4 layout.
// ---------------------------------------------------------------------------
__global__ __launch_bounds__(256) void gemm_qv(
    const float* __restrict__ x,
    const float* __restrict__ Wq,
    const float* __restrict__ Wv,
    float* __restrict__ Qb,
    float* __restrict__ Vb)
{
    constexpr int BM = 128, BN = 128, BK = 8;
    __shared__ float As[BK][BM];   // transposed A tile: As[k][m]
    __shared__ float Bs[BK][BN];

    const int tid  = threadIdx.x;
    const int row0 = blockIdx.y * BM;           // over B*N = 8192
    const int col0 = blockIdx.x * BN;           // over 1024 fused cols
    const bool isQ = (col0 < 512);
    const float* W = isQ ? Wq : Wv;
    const int wcol0 = col0 & 511;

    // A tile load: one float4 per thread. 128 rows x 8 k.
    const int a_r = tid >> 1;          // 0..127
    const int a_c = (tid & 1) * 4;     // 0 or 4
    // B tile load: one float4 per thread. 8 k x 128 cols.
    const int b_r = tid >> 5;          // 0..7
    const int b_c = (tid & 31) * 4;    // 0..124

    const int ty = tid >> 4;           // 0..15 -> row groups
    const int tx = tid & 15;           // 0..15 -> col groups

    float acc[8][8];
#pragma unroll
    for (int i = 0; i < 8; i++)
#pragma unroll
        for (int j = 0; j < 8; j++) acc[i][j] = 0.f;

    for (int k0 = 0; k0 < DMODEL; k0 += BK) {
        const float4 av = *(const float4*)(x + (size_t)(row0 + a_r) * DMODEL + k0 + a_c);
        const int cg = wcol0 + b_c;            // global col in [0,512)
        const int h  = cg >> 6;
        const int kk = cg & 63;
        const float4 bv = *(const float4*)(W + ((size_t)h * DMODEL + (k0 + b_r)) * DHEAD + kk);

        __syncthreads();   // previous iteration's LDS reads done
        As[a_c + 0][a_r] = av.x;
        As[a_c + 1][a_r] = av.y;
        As[a_c + 2][a_r] = av.z;
        As[a_c + 3][a_r] = av.w;
        *(float4*)&Bs[b_r][b_c] = bv;
        __syncthreads();

#pragma unroll
        for (int k = 0; k < BK; k++) {
            float a[8], b[8];
            *(float4*)(a)     = *(const float4*)&As[k][ty * 4];
            *(float4*)(a + 4) = *(const float4*)&As[k][ty * 4 + 64];
            *(float4*)(b)     = *(const float4*)&Bs[k][tx * 4];
            *(float4*)(b + 4) = *(const float4*)&Bs[k][tx * 4 + 64];
#pragma unroll
            for (int i = 0; i < 8; i++)
#pragma unroll
                for (int j = 0; j < 8; j++) acc[i][j] += a[i] * b[j];
        }
    }

    // Epilogue: scatter into [B, H, N, 64]
    float* outBase = isQ ? Qb : Vb;
#pragma unroll
    for (int ig = 0; ig < 2; ig++) {
#pragma unroll
        for (int ii = 0; ii < 4; ii++) {
            const int r  = row0 + ig * 64 + ty * 4 + ii;
            const int bb = r >> 12;
            const int n  = r & (N_TOK - 1);
#pragma unroll
            for (int jg = 0; jg < 2; jg++) {
                const int c  = wcol0 + tx * 4 + jg * 64;
                const int h  = c >> 6;
                const int kk = c & 63;
                float4 v;
                v.x = acc[ig * 4 + ii][jg * 4 + 0];
                v.y = acc[ig * 4 + ii][jg * 4 + 1];
                v.z = acc[ig * 4 + ii][jg * 4 + 2];
                v.w = acc[ig * 4 + ii][jg * 4 + 3];
                *(float4*)(outBase + (((size_t)(bb * NHEAD + h) * N_TOK + n) * DHEAD + kk)) = v;
            }
        }
    }
}

// ---------------------------------------------------------------------------
// Stage 2: banded attention. One thread per (b, h, i).
// Only |i-j| <= 10, j != i survive the mask (exp(-1e9) == 0 in fp32).
// Fixed 21-iteration unrolled loop with clamped addresses keeps s[] in regs.
// Output written directly in heads layout [B, N, H*64].
// ---------------------------------------------------------------------------
__global__ __launch_bounds__(256) void attn_band(
    const float* __restrict__ Qb,
    const float* __restrict__ Vb,
    float* __restrict__ Hb)
{
    const int t  = blockIdx.x * 256 + threadIdx.x;   // (b*H + h)*N + i
    const int i  = t & (N_TOK - 1);
    const int bh = t >> 12;

    const float4* qp = (const float4*)(Qb + (size_t)t * DHEAD);
    float4 q[16];
#pragma unroll
    for (int k = 0; k < 16; k++) q[k] = qp[k];

    const float* vbase = Vb + (size_t)bh * N_TOK * DHEAD;

    float s[2 * CTX + 1];
    float m = -3.0e38f;
#pragma unroll
    for (int d = 0; d < 2 * CTX + 1; d++) {
        const int j = i + d - CTX;
        const bool valid = (d != CTX) && (j >= 0) && (j < N_TOK);
        const int jc = min(max(j, 0), N_TOK - 1);
        const float4* vp = (const float4*)(vbase + (size_t)jc * DHEAD);
        float acc = 0.f;
#pragma unroll
        for (int k = 0; k < 16; k++) {
            const float4 v = vp[k];
            acc += q[k].x * v.x + q[k].y * v.y + q[k].z * v.z + q[k].w * v.w;
        }
        s[d] = valid ? acc * 0.0625f : -3.0e38f;
        m = fmaxf(m, s[d]);
    }

    float Z = 0.f;
#pragma unroll
    for (int d = 0; d < 2 * CTX + 1; d++) {
        s[d] = __expf(s[d] - m);    // invalid -> exp(very negative) == 0
        Z += s[d];
    }

    float4 c[16];
#pragma unroll
    for (int k = 0; k < 16; k++) c[k] = make_float4(0.f, 0.f, 0.f, 0.f);

#pragma unroll
    for (int d = 0; d < 2 * CTX + 1; d++) {
        const int j = i + d - CTX;
        const int jc = min(max(j, 0), N_TOK - 1);
        const float4* vp = (const float4*)(vbase + (size_t)jc * DHEAD);
        const float w = s[d];
#pragma unroll
        for (int k = 0; k < 16; k++) {
            const float4 v = vp[k];
            c[k].x += w * v.x;
            c[k].y += w * v.y;
            c[k].z += w * v.z;
            c[k].w += w * v.w;
        }
    }

    const float inv = 1.f / Z;
    const int b = bh >> 3, h = bh & 7;
    float4* op = (float4*)(Hb + ((size_t)(b * N_TOK + i) * (NHEAD * DHEAD) + h * DHEAD));
#pragma unroll
    for (int k = 0; k < 16; k++) {
        float4 v;
        v.x = c[k].x * inv;
        v.y = c[k].y * inv;
        v.z = c[k].z * inv;
        v.w = c[k].w * inv;
        op[k] = v;
    }
}

// ---------------------------------------------------------------------------
// Stage 3: output projection. heads[8192, 512] @ Wup[512, 512] -> out.
// Same tiling as stage 1, plain row-major layouts.
// ---------------------------------------------------------------------------
__global__ __launch_bounds__(256) void gemm_out(
    const float* __restrict__ A,     // heads [8192, 512]
    const float* __restrict__ Bw,    // Wup [512, 512]
    float* __restrict__ out)         // [8192, 512]
{
    constexpr int BM = 128, BN = 128, BK = 8;
    __shared__ float As[BK][BM];
    __shared__ float Bs[BK][BN];

    const int tid  = threadIdx.x;
    const int row0 = blockIdx.y * BM;
    const int col0 = blockIdx.x * BN;

    const int a_r = tid >> 1;
    const int a_c = (tid & 1) * 4;
    const int b_r = tid >> 5;
    const int b_c = (tid & 31) * 4;

    const int ty = tid >> 4;
    const int tx = tid & 15;

    float acc[8][8];
#pragma unroll
    for (int i = 0; i < 8; i++)
#pragma unroll
        for (int j = 0; j < 8; j++) acc[i][j] = 0.f;

    for (int k0 = 0; k0 < DMODEL; k0 += BK) {
        const float4 av = *(const float4*)(A + (size_t)(row0 + a_r) * DMODEL + k0 + a_c);
        const float4 bv = *(const float4*)(Bw + (size_t)(k0 + b_r) * DMODEL + col0 + b_c);

        __syncthreads();
        As[a_c + 0][a_r] = av.x;
        As[a_c + 1][a_r] = av.y;
        As[a_c + 2][a_r] = av.z;
        As[a_c + 3][a_r] = av.w;
        *(float4*)&Bs[b_r][b_c] = bv;
        __syncthreads();

#pragma unroll
        for (int k = 0; k < BK; k++) {
            float a[8], b[8];
            *(float4*)(a)     = *(const float4*)&As[k][ty * 4];
            *(float4*)(a + 4) = *(const float4*)&As[k][ty * 4 + 64];
            *(float4*)(b)     = *(const float4*)&Bs[k][tx * 4];
            *(float4*)(b + 4) = *(const float4*)&Bs[k][tx * 4 + 64];
#pragma unroll
            for (int i = 0; i < 8; i++)
#pragma unroll
                for (int j = 0; j < 8; j++) acc[i][j] += a[i] * b[j];
        }
    }

#pragma unroll
    for (int ig = 0; ig < 2; ig++) {
#pragma unroll
        for (int ii = 0; ii < 4; ii++) {
            const int r = row0 + ig * 64 + ty * 4 + ii;
#pragma unroll
            for (int jg = 0; jg < 2; jg++) {
                const int c = col0 + tx * 4 + jg * 64;
                float4 v;
                v.x = acc[ig * 4 + ii][jg * 4 + 0];
                v.y = acc[ig * 4 + ii][jg * 4 + 1];
                v.z = acc[ig * 4 + ii][jg * 4 + 2];
                v.w = acc[ig * 4 + ii][jg * 4 + 3];
                *(float4*)(out + (size_t)r * DMODEL + c) = v;
            }
        }
    }
}

// ---------------------------------------------------------------------------
extern "C" void kernel_launch(void* const* d_in, const int* in_sizes, int n_in,
                              void* d_out, int out_size, void* d_ws, size_t ws_size,
                              hipStream_t stream)
{
    const float* x   = (const float*)d_in[0];   // [2, 4096, 512]
    const float* Wq  = (const float*)d_in[1];   // [8, 512, 64]
    const float* Wv  = (const float*)d_in[2];   // [8, 512, 64]
    const float* Wup = (const float*)d_in[3];   // [512, 512]
    float* out = (float*)d_out;                 // [2, 4096, 512]

    const size_t QV = (size_t)2 * NHEAD * N_TOK * DHEAD;  // 4,194,304 floats
    float* Qb = (float*)d_ws;
    float* Vb = Qb + QV;
    float* Hb = Vb + QV;

    dim3 blk(256);
    // Stage 1: [8192x512] @ [512x1024] fused Q|V
    gemm_qv<<<dim3(8, 64), blk, 0, stream>>>(x, Wq, Wv, Qb, Vb);
    // Stage 2: banded softmax-attention, 1 thread per (b,h,i)
    attn_band<<<dim3((2 * NHEAD * N_TOK) / 256), blk, 0, stream>>>(Qb, Vb, Hb);
    // Stage 3: [8192x512] @ [512x512]
    gemm_out<<<dim3(4, 64), blk, 0, stream>>>(Hb, Wup, out);
}